// Round 12
// baseline (332.690 us; speedup 1.0000x reference)
//
#include <hip/hip_runtime.h>

#define ZC     256
#define KCODES 1024
#define MARGIN 4e-4f   // hi-only bf16 GEMM: gap-error sigma ~4e-5 -> 10 sigma

typedef __attribute__((ext_vector_type(4))) float f32x4;
typedef __attribute__((ext_vector_type(8))) short s16x8;
typedef unsigned int u32t;
typedef u32t __attribute__((address_space(1))) as1_u32;
typedef u32t __attribute__((address_space(3))) as3_u32;

__device__ __forceinline__ void glds16(const void* g, void* l) {
    __builtin_amdgcn_global_load_lds((const as1_u32*)g, (as3_u32*)l, 16, 0, 0);
}
__device__ __forceinline__ unsigned short bf16_rn(float x) {
    union { float f; u32t u; } v; v.f = x;
    return (unsigned short)((v.u + 0x7FFFu + ((v.u >> 16) & 1u)) >> 16);
}

// ---------------------------------------------------------------------------
// prep_z: z fp32 [32,256,32,32] -> A' bf16 [4 kblk][32768 pt][64 k] (HI ONLY),
// swizzle baked in global layout: short col = k ^ ((pt&7)<<3). (r7-verified
// addressing; lo-residual plane dropped -> half the writes.)
// ---------------------------------------------------------------------------
__global__ __launch_bounds__(256)
void vq_prep_z(const float* __restrict__ z, unsigned short* __restrict__ Ab)
{
    const int t = threadIdx.x, blk = blockIdx.x;
    const int pt = (blk >> 3) * 64 + (t & 63);
    const int c0 = (blk & 7) * 32 + (t >> 6) * 8;
    const int b = pt >> 10, hw = pt & 1023;
    const float* zp = z + (size_t)b * (ZC * 1024) + (size_t)c0 * 1024 + hw;

    unsigned short hi[8];
    #pragma unroll
    for (int j = 0; j < 8; ++j) hi[j] = bf16_rn(zp[(size_t)j * 1024]);
    uint4 ph;
    ph.x = (u32t)hi[0] | ((u32t)hi[1] << 16); ph.y = (u32t)hi[2] | ((u32t)hi[3] << 16);
    ph.z = (u32t)hi[4] | ((u32t)hi[5] << 16); ph.w = (u32t)hi[6] | ((u32t)hi[7] << 16);

    const size_t kb = (size_t)(c0 >> 6);
    const int sw = (c0 & 63) ^ ((pt & 7) << 3);
    *reinterpret_cast<uint4*>(Ab + kb * (32768ull * 64) + (size_t)pt * 64 + sw) = ph;
}

// ---------------------------------------------------------------------------
// prep_e: emb fp32 [1024,256] -> B' bf16 [4 kblk][1024 code][64], same swizzle.
// ---------------------------------------------------------------------------
__global__ __launch_bounds__(256)
void vq_prep_e(const float* __restrict__ emb, unsigned short* __restrict__ Bb)
{
    const int t = threadIdx.x, blk = blockIdx.x;
    const int code = (blk >> 3) * 64 + (t & 63);
    const int c0 = (blk & 7) * 32 + (t >> 6) * 8;
    const float* ep = emb + (size_t)code * ZC + c0;

    unsigned short hi[8];
    #pragma unroll
    for (int j = 0; j < 8; ++j) hi[j] = bf16_rn(ep[j]);
    uint4 ph;
    ph.x = (u32t)hi[0] | ((u32t)hi[1] << 16); ph.y = (u32t)hi[2] | ((u32t)hi[3] << 16);
    ph.z = (u32t)hi[4] | ((u32t)hi[5] << 16); ph.w = (u32t)hi[6] | ((u32t)hi[7] << 16);

    const size_t kb = (size_t)(c0 >> 6);
    const int sw = (c0 & 63) ^ ((code & 7) << 3);
    *reinterpret_cast<uint4*>(Bb + kb * (1024ull * 64) + (size_t)code * 64 + sw) = ph;
}

// ---------------------------------------------------------------------------
// ens: codebook squared norms -> ens_g[1024]; zeroes fixup counter.
// ---------------------------------------------------------------------------
__global__ __launch_bounds__(256)
void vq_ens(const float* __restrict__ emb, float* __restrict__ ens_g,
            int* __restrict__ cnt)
{
    if (blockIdx.x == 0 && threadIdx.x == 0) *cnt = 0;
    const int t = threadIdx.x, lane = t & 63, w = t >> 6;
    for (int rep = 0; rep < 16; ++rep) {
        const int k = blockIdx.x * 64 + rep * 4 + w;
        const float4 v = *reinterpret_cast<const float4*>(emb + (size_t)k * ZC + lane * 4);
        float s = v.x * v.x + v.y * v.y + v.z * v.z + v.w * v.w;
        #pragma unroll
        for (int m = 1; m < 64; m <<= 1) s += __shfl_xor(s, m);
        if (lane == 0) ens_g[k] = s;
    }
}

// ---------------------------------------------------------------------------
// GEMM+argmin: r7-verified skeleton (512 blocks, 64 pts x 1024 codes, 4 waves,
// 24 KB LDS, 2-barrier k-step, direct out_idx write). Only change: K=256
// hi-only -> 4 k-steps per code-tile (kbA = kbB = ks), MARGIN widened.
// ---------------------------------------------------------------------------
__global__ __launch_bounds__(256, 2)
void vq_gemm_argmin(const unsigned short* __restrict__ Ab,
                    const unsigned short* __restrict__ Bb,
                    const float* __restrict__ ens_g, float* __restrict__ out_idx)
{
    __shared__ unsigned short As[64 * 64];     // 8 KB, linear (glds dest)
    __shared__ unsigned short Bs[128 * 64];    // 16 KB, linear

    const int t = threadIdx.x;
    const int lane = t & 63, wv = t >> 6;
    const int col = lane & 15, kg = lane >> 4;
    const int pt0 = blockIdx.x * 64;
    const int kx = (col & 7) << 3;             // read-side XOR (shorts)

    int aoff[4][2], boff[2][2];                // offsets in shorts
    #pragma unroll
    for (int m = 0; m < 4; ++m)
        #pragma unroll
        for (int s = 0; s < 2; ++s)
            aoff[m][s] = (m * 16 + col) * 64 + ((s * 32 + kg * 8) ^ kx);
    #pragma unroll
    for (int n = 0; n < 2; ++n)
        #pragma unroll
        for (int s = 0; s < 2; ++s)
            boff[n][s] = (wv * 32 + n * 16 + col) * 64 + ((s * 32 + kg * 8) ^ kx);

    f32x4 acc[4][2];
    #pragma unroll
    for (int m = 0; m < 4; ++m)
        #pragma unroll
        for (int n = 0; n < 2; ++n) acc[m][n] = (f32x4){0.f, 0.f, 0.f, 0.f};

    float v1[16], v2[16]; int id1[16];
    #pragma unroll
    for (int i = 0; i < 16; ++i) { v1[i] = 3.4e38f; v2[i] = 3.4e38f; id1[i] = 0; }

    for (int ct = 0; ct < 8; ++ct) {
        for (int ks = 0; ks < 4; ++ks) {
            const char* aS = (const char*)(Ab + (size_t)ks * 2097152ull + (size_t)pt0 * 64);
            const char* bS = (const char*)(Bb + (size_t)ks * 65536ull + (size_t)ct * 8192);

            __syncthreads();   // prior k-step's LDS reads complete
            glds16(aS + t * 16,        (char*)As + t * 16);
            glds16(aS + 4096 + t * 16, (char*)As + 4096 + t * 16);
            #pragma unroll
            for (int q = 0; q < 4; ++q)
                glds16(bS + q * 4096 + t * 16, (char*)Bs + q * 4096 + t * 16);
            __syncthreads();   // drains vmcnt before barrier

            s16x8 af[4][2], bf[2][2];
            #pragma unroll
            for (int m = 0; m < 4; ++m)
                #pragma unroll
                for (int s = 0; s < 2; ++s)
                    af[m][s] = *reinterpret_cast<const s16x8*>(As + aoff[m][s]);
            #pragma unroll
            for (int n = 0; n < 2; ++n)
                #pragma unroll
                for (int s = 0; s < 2; ++s)
                    bf[n][s] = *reinterpret_cast<const s16x8*>(Bs + boff[n][s]);
            #pragma unroll
            for (int m = 0; m < 4; ++m)
                #pragma unroll
                for (int n = 0; n < 2; ++n) {
                    acc[m][n] = __builtin_amdgcn_mfma_f32_16x16x32_bf16(af[m][0], bf[n][0], acc[m][n], 0, 0, 0);
                    acc[m][n] = __builtin_amdgcn_mfma_f32_16x16x32_bf16(af[m][1], bf[n][1], acc[m][n], 0, 0, 0);
                }

            if (ks == 3) {   // code-tile epilogue: top-2 update, reset acc
                #pragma unroll
                for (int n = 0; n < 2; ++n) {
                    const int code = ct * 128 + wv * 32 + n * 16 + col;
                    const float en = ens_g[code];
                    #pragma unroll
                    for (int m = 0; m < 4; ++m)
                        #pragma unroll
                        for (int j = 0; j < 4; ++j) {
                            const float sc = fmaf(-2.f, acc[m][n][j], en);
                            const int sl = m * 4 + j;
                            if (sc < v1[sl]) { v2[sl] = v1[sl]; v1[sl] = sc; id1[sl] = code; }
                            else if (sc < v2[sl]) { v2[sl] = sc; }
                            acc[m][n][j] = 0.f;
                        }
                }
            }
        }
    }

    // in-wave 16-lane top-2 merge (verified rounds 5-11)
    float w1[16], w2[16]; int wid[16];
    #pragma unroll
    for (int sl = 0; sl < 16; ++sl) {
        float a1 = v1[sl]; int ai = id1[sl]; float a2 = v2[sl];
        #pragma unroll
        for (int mk = 1; mk < 16; mk <<= 1) {
            const float o1 = __shfl_xor(a1, mk);
            const int   oi = __shfl_xor(ai, mk);
            const float o2 = __shfl_xor(a2, mk);
            if (o1 < a1)      { a2 = fminf(a1, o2); a1 = o1; ai = oi; }
            else if (o1 > a1) { a2 = fminf(a2, o1); }
            else              { a2 = (oi != ai) ? a1 : fminf(a2, o2); ai = (oi < ai) ? oi : ai; }
        }
        w1[sl] = a1; w2[sl] = a2; wid[sl] = ai;
    }

    // cross-wave merge via LDS (verified rounds 5-11)
    __syncthreads();
    float* mv1 = reinterpret_cast<float*>(As);
    float* mv2 = mv1 + 256;
    int*   mid = reinterpret_cast<int*>(mv2 + 256);
    if (col == 0) {
        #pragma unroll
        for (int sl = 0; sl < 16; ++sl) {
            const int m = sl >> 2, j = sl & 3;
            const int p = m * 16 + kg * 4 + j;
            mv1[wv * 64 + p] = w1[sl];
            mv2[wv * 64 + p] = w2[sl];
            mid[wv * 64 + p] = wid[sl];
        }
    }
    __syncthreads();
    if (t < 64) {
        float a1 = mv1[t], a2 = mv2[t]; int ai = mid[t];
        #pragma unroll
        for (int w = 1; w < 4; ++w) {
            const float b1 = mv1[w * 64 + t], b2 = mv2[w * 64 + t];
            const int   bi = mid[w * 64 + t];
            if (b1 < a1)      { a2 = fminf(a1, b2); a1 = b1; ai = bi; }
            else if (b1 > a1) { a2 = fminf(a2, b1); }
            else              { a2 = a1; ai = (bi < ai) ? bi : ai; }
        }
        out_idx[pt0 + t] = ((a2 - a1) <= MARGIN) ? (-1.0f - (float)ai) : (float)ai;
    }
}

// ---------------------------------------------------------------------------
// compact: flagged points -> worklist.
// ---------------------------------------------------------------------------
__global__ __launch_bounds__(256)
void vq_compact(const float* __restrict__ idxf, int* __restrict__ cnt,
                int* __restrict__ list)
{
    const int n = blockIdx.x * 256 + threadIdx.x;
    if (idxf[n] < 0.f) { const int p = atomicAdd(cnt, 1); list[p] = n; }
}

// ---------------------------------------------------------------------------
// numpy pairwise-sum replication (verified round 2).
// ---------------------------------------------------------------------------
__device__ __forceinline__ float np_pair128_sq(const float* __restrict__ a) {
    float r[8];
    #pragma unroll
    for (int j = 0; j < 8; ++j) r[j] = __fmul_rn(a[j], a[j]);
    #pragma unroll
    for (int i = 8; i < 128; i += 8)
        #pragma unroll
        for (int j = 0; j < 8; ++j) r[j] = __fadd_rn(r[j], __fmul_rn(a[i + j], a[i + j]));
    const float s01 = __fadd_rn(r[0], r[1]);
    const float s23 = __fadd_rn(r[2], r[3]);
    const float s45 = __fadd_rn(r[4], r[5]);
    const float s67 = __fadd_rn(r[6], r[7]);
    return __fadd_rn(__fadd_rn(s01, s23), __fadd_rn(s45, s67));
}
__device__ __forceinline__ float np_sum256_sq(const float* __restrict__ a) {
    return __fadd_rn(np_pair128_sq(a), np_pair128_sq(a + 128));
}

// ---------------------------------------------------------------------------
// fixup2 (verified round 6, numerics untouched): one block per flagged point,
// np-exact adjudication. Grid widened 512 -> 2048 for the larger flag count
// that the wider MARGIN produces (~1 point per block).
// ---------------------------------------------------------------------------
__global__ __launch_bounds__(256)
void vq_fixup2(const float* __restrict__ z, const float* __restrict__ emb,
               float* __restrict__ idxf, const int* __restrict__ cnt,
               const int* __restrict__ list)
{
    __shared__ float zs[ZC];
    __shared__ float es[32 * 264];
    __shared__ float gbv[32];
    __shared__ int   gbk[32];

    const int t = threadIdx.x;
    const int g = t >> 3, r = t & 7;
    const int C = *cnt;

    for (int it = blockIdx.x; it < C; it += 2048) {
        const int n = list[it];
        const int b = n >> 10, q = n & 1023;
        __syncthreads();
        zs[t] = z[(size_t)b * (ZC * 1024) + (size_t)t * 1024 + q];
        __syncthreads();

        const float zn = np_sum256_sq(zs);

        float best = 3.4e38f; int bestk = 0x7fffffff;

        for (int tile = 0; tile < 32; ++tile) {
            __syncthreads();
            const float4* src = reinterpret_cast<const float4*>(emb + (size_t)tile * 32 * ZC);
            #pragma unroll
            for (int i = 0; i < 8; ++i) {
                const int f = i * 256 + t;
                const int row = f >> 6, c4 = f & 63;
                *reinterpret_cast<float4*>(es + row * 264 + c4 * 4) = src[f];
            }
            __syncthreads();

            const float* er = es + g * 264;
            float lo, hi;
            double dd;
            {
                const float a0 = er[r];
                const float a1 = er[128 + r];
                lo = __fmul_rn(a0, a0);
                hi = __fmul_rn(a1, a1);
                dd = fma((double)a0, (double)zs[r],
                     fma((double)a1, (double)zs[128 + r], 0.0));
            }
            #pragma unroll
            for (int i = 1; i < 16; ++i) {
                const int c = 8 * i + r;
                const float a0 = er[c];
                const float a1 = er[128 + c];
                lo = __fadd_rn(lo, __fmul_rn(a0, a0));
                hi = __fadd_rn(hi, __fmul_rn(a1, a1));
                dd = fma((double)a0, (double)zs[c], dd);
                dd = fma((double)a1, (double)zs[128 + c], dd);
            }
            #pragma unroll
            for (int mk = 1; mk < 8; mk <<= 1) {
                lo = __fadd_rn(lo, __shfl_xor(lo, mk));
                hi = __fadd_rn(hi, __shfl_xor(hi, mk));
                dd = dd + __shfl_xor(dd, mk);
            }
            if (r == 0) {
                const float en  = __fadd_rn(lo, hi);
                const float t2f = (float)dd;
                const float d   = __fsub_rn(__fadd_rn(zn, en), __fmul_rn(2.0f, t2f));
                const int code  = tile * 32 + g;
                if (d < best) { best = d; bestk = code; }
            }
        }

        if (r == 0) { gbv[g] = best; gbk[g] = bestk; }
        __syncthreads();
        if (t == 0) {
            float bv = gbv[0]; int bk = gbk[0];
            for (int gg = 1; gg < 32; ++gg)
                if (gbv[gg] < bv || (gbv[gg] == bv && gbk[gg] < bk)) { bv = gbv[gg]; bk = gbk[gg]; }
            idxf[n] = (float)bk;
        }
        __syncthreads();
    }
}

// ---------------------------------------------------------------------------
// outputs (verified round 2) — overwrites the scratch regions.
// ---------------------------------------------------------------------------
__global__ __launch_bounds__(256)
void vq_outputs_kernel(const float* __restrict__ z, const float* __restrict__ emb,
                       const float* __restrict__ idxf,
                       float* __restrict__ out_q, float* __restrict__ out_loss)
{
    __shared__ float zts[32 * 257];
    __shared__ int   ids[32];

    const int t  = threadIdx.x;
    const int bh = blockIdx.x;
    const int b  = bh >> 5, h = bh & 31;
    const int n0 = bh * 32;

    if (t < 32) ids[t] = (int)idxf[n0 + t];
    __syncthreads();

    const size_t zbase = (size_t)b * (ZC * 1024) + h * 32;

    for (int rep = 0; rep < 32; ++rep) {
        const int flat = rep * 256 + t;
        const int c = flat >> 5;
        const int ww = flat & 31;
        const size_t ga = zbase + (size_t)c * 1024 + ww;
        const float zv = z[ga];
        zts[ww * 257 + c] = zv;
        out_q[ga] = emb[(size_t)ids[ww] * ZC + c];
    }
    __syncthreads();

    for (int rep = 0; rep < 32; ++rep) {
        const float e = emb[(size_t)ids[rep] * ZC + t];
        const float d = e - zts[rep * 257 + t];
        out_loss[(size_t)(n0 + rep) * ZC + t] = 1.25f * d * d;
    }
}

extern "C" void kernel_launch(void* const* d_in, const int* in_sizes, int n_in,
                              void* d_out, int out_size, void* d_ws, size_t ws_size,
                              hipStream_t stream)
{
    const float* z   = (const float*)d_in[0];   // [32,256,32,32]
    const float* emb = (const float*)d_in[1];   // [1024,256]
    float* out      = (float*)d_out;
    float* out_q    = out;                       // 8388608 floats
    float* out_loss = out + 8388608;             // 8388608 floats
    float* out_idx  = out + 16777216;            // 32768 floats

    // scratch carved from output regions (fully overwritten by final kernels):
    unsigned short* Ab = (unsigned short*)d_out;                       // 16 MiB (out_q)
    unsigned short* Bb = (unsigned short*)((char*)d_out + 33554432);   // 512 KiB
    float* ensg = (float*)((char*)d_out + 34603008);                   // 4 KiB
    int*   cnt  = (int*)  ((char*)d_out + 34607104);                   // 4 B
    int*   list = (int*)  ((char*)d_out + 34607168);                   // 128 KiB

    vq_prep_z        <<<4096, 256, 0, stream>>>(z, Ab);
    vq_prep_e        <<<128,  256, 0, stream>>>(emb, Bb);
    vq_ens           <<<16,   256, 0, stream>>>(emb, ensg, cnt);
    vq_gemm_argmin   <<<512,  256, 0, stream>>>(Ab, Bb, ensg, out_idx);
    vq_compact       <<<128,  256, 0, stream>>>(out_idx, cnt, list);
    vq_fixup2        <<<2048, 256, 0, stream>>>(z, emb, out_idx, cnt, list);
    vq_outputs_kernel<<<1024, 256, 0, stream>>>(z, emb, out_idx, out_q, out_loss);
}

// Round 13
// 281.641 us; speedup vs baseline: 1.1813x; 1.1813x over previous
//
#include <hip/hip_runtime.h>

#define ZC     256
#define KCODES 1024
#define MARGIN 4e-4f   // hi-only bf16 GEMM: gap-error sigma ~4e-5 -> 10 sigma

typedef __attribute__((ext_vector_type(4))) float f32x4;
typedef __attribute__((ext_vector_type(8))) short s16x8;
typedef unsigned int u32t;
typedef u32t __attribute__((address_space(1))) as1_u32;
typedef u32t __attribute__((address_space(3))) as3_u32;

__device__ __forceinline__ void glds16(const void* g, void* l) {
    __builtin_amdgcn_global_load_lds((const as1_u32*)g, (as3_u32*)l, 16, 0, 0);
}
__device__ __forceinline__ unsigned short bf16_rn(float x) {
    union { float f; u32t u; } v; v.f = x;
    return (unsigned short)((v.u + 0x7FFFu + ((v.u >> 16) & 1u)) >> 16);
}

// ---------------------------------------------------------------------------
// prep_z: z fp32 [32,256,32,32] -> A' bf16 [4 kblk][32768 pt][64 k] (HI ONLY),
// swizzle baked in global layout: short col = k ^ ((pt&7)<<3). (verified r12)
// ---------------------------------------------------------------------------
__global__ __launch_bounds__(256)
void vq_prep_z(const float* __restrict__ z, unsigned short* __restrict__ Ab)
{
    const int t = threadIdx.x, blk = blockIdx.x;
    const int pt = (blk >> 3) * 64 + (t & 63);
    const int c0 = (blk & 7) * 32 + (t >> 6) * 8;
    const int b = pt >> 10, hw = pt & 1023;
    const float* zp = z + (size_t)b * (ZC * 1024) + (size_t)c0 * 1024 + hw;

    unsigned short hi[8];
    #pragma unroll
    for (int j = 0; j < 8; ++j) hi[j] = bf16_rn(zp[(size_t)j * 1024]);
    uint4 ph;
    ph.x = (u32t)hi[0] | ((u32t)hi[1] << 16); ph.y = (u32t)hi[2] | ((u32t)hi[3] << 16);
    ph.z = (u32t)hi[4] | ((u32t)hi[5] << 16); ph.w = (u32t)hi[6] | ((u32t)hi[7] << 16);

    const size_t kb = (size_t)(c0 >> 6);
    const int sw = (c0 & 63) ^ ((pt & 7) << 3);
    *reinterpret_cast<uint4*>(Ab + kb * (32768ull * 64) + (size_t)pt * 64 + sw) = ph;
}

// ---------------------------------------------------------------------------
// prep_e: emb fp32 [1024,256] -> B' bf16 [4 kblk][1024 code][64], same swizzle.
// ---------------------------------------------------------------------------
__global__ __launch_bounds__(256)
void vq_prep_e(const float* __restrict__ emb, unsigned short* __restrict__ Bb)
{
    const int t = threadIdx.x, blk = blockIdx.x;
    const int code = (blk >> 3) * 64 + (t & 63);
    const int c0 = (blk & 7) * 32 + (t >> 6) * 8;
    const float* ep = emb + (size_t)code * ZC + c0;

    unsigned short hi[8];
    #pragma unroll
    for (int j = 0; j < 8; ++j) hi[j] = bf16_rn(ep[j]);
    uint4 ph;
    ph.x = (u32t)hi[0] | ((u32t)hi[1] << 16); ph.y = (u32t)hi[2] | ((u32t)hi[3] << 16);
    ph.z = (u32t)hi[4] | ((u32t)hi[5] << 16); ph.w = (u32t)hi[6] | ((u32t)hi[7] << 16);

    const size_t kb = (size_t)(c0 >> 6);
    const int sw = (c0 & 63) ^ ((code & 7) << 3);
    *reinterpret_cast<uint4*>(Bb + kb * (1024ull * 64) + (size_t)code * 64 + sw) = ph;
}

// ---------------------------------------------------------------------------
// ens_np: np-pairwise-EXACT codebook norms (the verified fixup2 tree: 8-lane
// chains of 16 + fadd butterfly = numpy pairwise_sum for n=256). Computed
// ONCE, used by both GEMM epilogue and fixup3. Also zeroes fixup counter.
// ---------------------------------------------------------------------------
__global__ __launch_bounds__(256)
void vq_ens_np(const float* __restrict__ emb, float* __restrict__ ens_np,
               int* __restrict__ cnt)
{
    if (blockIdx.x == 0 && threadIdx.x == 0) *cnt = 0;
    const int t = threadIdx.x, g = t >> 3, r = t & 7;
    const int code = blockIdx.x * 32 + g;
    const float* er = emb + (size_t)code * ZC;

    float lo, hi;
    {
        const float a0 = er[r], a1 = er[128 + r];
        lo = __fmul_rn(a0, a0); hi = __fmul_rn(a1, a1);
    }
    #pragma unroll
    for (int i = 1; i < 16; ++i) {
        const int c = 8 * i + r;
        const float a0 = er[c], a1 = er[128 + c];
        lo = __fadd_rn(lo, __fmul_rn(a0, a0));
        hi = __fadd_rn(hi, __fmul_rn(a1, a1));
    }
    #pragma unroll
    for (int mk = 1; mk < 8; mk <<= 1) {
        lo = __fadd_rn(lo, __shfl_xor(lo, mk));
        hi = __fadd_rn(hi, __shfl_xor(hi, mk));
    }
    if (r == 0) ens_np[code] = __fadd_rn(lo, hi);
}

// ---------------------------------------------------------------------------
// GEMM+argmin (verified r12, unchanged): 512 blocks, 64 pts x 1024 codes,
// 4 waves, 24 KB LDS, K=256 hi-only (4 k-steps/ct), flag-encoded out_idx.
// ---------------------------------------------------------------------------
__global__ __launch_bounds__(256, 2)
void vq_gemm_argmin(const unsigned short* __restrict__ Ab,
                    const unsigned short* __restrict__ Bb,
                    const float* __restrict__ ens_g, float* __restrict__ out_idx)
{
    __shared__ unsigned short As[64 * 64];
    __shared__ unsigned short Bs[128 * 64];

    const int t = threadIdx.x;
    const int lane = t & 63, wv = t >> 6;
    const int col = lane & 15, kg = lane >> 4;
    const int pt0 = blockIdx.x * 64;
    const int kx = (col & 7) << 3;

    int aoff[4][2], boff[2][2];
    #pragma unroll
    for (int m = 0; m < 4; ++m)
        #pragma unroll
        for (int s = 0; s < 2; ++s)
            aoff[m][s] = (m * 16 + col) * 64 + ((s * 32 + kg * 8) ^ kx);
    #pragma unroll
    for (int n = 0; n < 2; ++n)
        #pragma unroll
        for (int s = 0; s < 2; ++s)
            boff[n][s] = (wv * 32 + n * 16 + col) * 64 + ((s * 32 + kg * 8) ^ kx);

    f32x4 acc[4][2];
    #pragma unroll
    for (int m = 0; m < 4; ++m)
        #pragma unroll
        for (int n = 0; n < 2; ++n) acc[m][n] = (f32x4){0.f, 0.f, 0.f, 0.f};

    float v1[16], v2[16]; int id1[16];
    #pragma unroll
    for (int i = 0; i < 16; ++i) { v1[i] = 3.4e38f; v2[i] = 3.4e38f; id1[i] = 0; }

    for (int ct = 0; ct < 8; ++ct) {
        for (int ks = 0; ks < 4; ++ks) {
            const char* aS = (const char*)(Ab + (size_t)ks * 2097152ull + (size_t)pt0 * 64);
            const char* bS = (const char*)(Bb + (size_t)ks * 65536ull + (size_t)ct * 8192);

            __syncthreads();
            glds16(aS + t * 16,        (char*)As + t * 16);
            glds16(aS + 4096 + t * 16, (char*)As + 4096 + t * 16);
            #pragma unroll
            for (int q = 0; q < 4; ++q)
                glds16(bS + q * 4096 + t * 16, (char*)Bs + q * 4096 + t * 16);
            __syncthreads();

            s16x8 af[4][2], bf[2][2];
            #pragma unroll
            for (int m = 0; m < 4; ++m)
                #pragma unroll
                for (int s = 0; s < 2; ++s)
                    af[m][s] = *reinterpret_cast<const s16x8*>(As + aoff[m][s]);
            #pragma unroll
            for (int n = 0; n < 2; ++n)
                #pragma unroll
                for (int s = 0; s < 2; ++s)
                    bf[n][s] = *reinterpret_cast<const s16x8*>(Bs + boff[n][s]);
            #pragma unroll
            for (int m = 0; m < 4; ++m)
                #pragma unroll
                for (int n = 0; n < 2; ++n) {
                    acc[m][n] = __builtin_amdgcn_mfma_f32_16x16x32_bf16(af[m][0], bf[n][0], acc[m][n], 0, 0, 0);
                    acc[m][n] = __builtin_amdgcn_mfma_f32_16x16x32_bf16(af[m][1], bf[n][1], acc[m][n], 0, 0, 0);
                }

            if (ks == 3) {
                #pragma unroll
                for (int n = 0; n < 2; ++n) {
                    const int code = ct * 128 + wv * 32 + n * 16 + col;
                    const float en = ens_g[code];
                    #pragma unroll
                    for (int m = 0; m < 4; ++m)
                        #pragma unroll
                        for (int j = 0; j < 4; ++j) {
                            const float sc = fmaf(-2.f, acc[m][n][j], en);
                            const int sl = m * 4 + j;
                            if (sc < v1[sl]) { v2[sl] = v1[sl]; v1[sl] = sc; id1[sl] = code; }
                            else if (sc < v2[sl]) { v2[sl] = sc; }
                            acc[m][n][j] = 0.f;
                        }
                }
            }
        }
    }

    float w1[16], w2[16]; int wid[16];
    #pragma unroll
    for (int sl = 0; sl < 16; ++sl) {
        float a1 = v1[sl]; int ai = id1[sl]; float a2 = v2[sl];
        #pragma unroll
        for (int mk = 1; mk < 16; mk <<= 1) {
            const float o1 = __shfl_xor(a1, mk);
            const int   oi = __shfl_xor(ai, mk);
            const float o2 = __shfl_xor(a2, mk);
            if (o1 < a1)      { a2 = fminf(a1, o2); a1 = o1; ai = oi; }
            else if (o1 > a1) { a2 = fminf(a2, o1); }
            else              { a2 = (oi != ai) ? a1 : fminf(a2, o2); ai = (oi < ai) ? oi : ai; }
        }
        w1[sl] = a1; w2[sl] = a2; wid[sl] = ai;
    }

    __syncthreads();
    float* mv1 = reinterpret_cast<float*>(As);
    float* mv2 = mv1 + 256;
    int*   mid = reinterpret_cast<int*>(mv2 + 256);
    if (col == 0) {
        #pragma unroll
        for (int sl = 0; sl < 16; ++sl) {
            const int m = sl >> 2, j = sl & 3;
            const int p = m * 16 + kg * 4 + j;
            mv1[wv * 64 + p] = w1[sl];
            mv2[wv * 64 + p] = w2[sl];
            mid[wv * 64 + p] = wid[sl];
        }
    }
    __syncthreads();
    if (t < 64) {
        float a1 = mv1[t], a2 = mv2[t]; int ai = mid[t];
        #pragma unroll
        for (int w = 1; w < 4; ++w) {
            const float b1 = mv1[w * 64 + t], b2 = mv2[w * 64 + t];
            const int   bi = mid[w * 64 + t];
            if (b1 < a1)      { a2 = fminf(a1, b2); a1 = b1; ai = bi; }
            else if (b1 > a1) { a2 = fminf(a2, b1); }
            else              { a2 = a1; ai = (bi < ai) ? bi : ai; }
        }
        out_idx[pt0 + t] = ((a2 - a1) <= MARGIN) ? (-1.0f - (float)ai) : (float)ai;
    }
}

// ---------------------------------------------------------------------------
// compact: flagged points -> worklist.
// ---------------------------------------------------------------------------
__global__ __launch_bounds__(256)
void vq_compact(const float* __restrict__ idxf, int* __restrict__ cnt,
                int* __restrict__ list)
{
    const int n = blockIdx.x * 256 + threadIdx.x;
    if (idxf[n] < 0.f) { const int p = atomicAdd(cnt, 1); list[p] = n; }
}

// ---------------------------------------------------------------------------
// numpy pairwise-sum replication (verified round 2) — used for z norms.
// ---------------------------------------------------------------------------
__device__ __forceinline__ float np_pair128_sq(const float* __restrict__ a) {
    float r[8];
    #pragma unroll
    for (int j = 0; j < 8; ++j) r[j] = __fmul_rn(a[j], a[j]);
    #pragma unroll
    for (int i = 8; i < 128; i += 8)
        #pragma unroll
        for (int j = 0; j < 8; ++j) r[j] = __fadd_rn(r[j], __fmul_rn(a[i + j], a[i + j]));
    const float s01 = __fadd_rn(r[0], r[1]);
    const float s23 = __fadd_rn(r[2], r[3]);
    const float s45 = __fadd_rn(r[4], r[5]);
    const float s67 = __fadd_rn(r[6], r[7]);
    return __fadd_rn(__fadd_rn(s01, s23), __fadd_rn(s45, s67));
}
__device__ __forceinline__ float np_sum256_sq(const float* __restrict__ a) {
    return __fadd_rn(np_pair128_sq(a), np_pair128_sq(a + 128));
}

// ---------------------------------------------------------------------------
// fixup3: np-exact adjudication, restructured from verified fixup2:
//  - code norms read from precomputed ens_np (hoisted, point-independent)
//  - 4 points batched per staged emb tile (staging amortized 4x)
//  - grid 2048 x stride-4 -> ~1 batch per block
// Numerics identical: same f64 dot -> f32 cast, same fl(fl(zn+en)-fl(2*t2)),
// same ascending-code first-min merge. Register trackers statically indexed.
// ---------------------------------------------------------------------------
__global__ __launch_bounds__(256)
void vq_fixup3(const float* __restrict__ z, const float* __restrict__ emb,
               const float* __restrict__ ens_np, float* __restrict__ idxf,
               const int* __restrict__ cnt, const int* __restrict__ list)
{
    __shared__ float es[32 * 264];    // 32 codes x 256 (stride 264)
    __shared__ float zsb[4 * 264];    // 4 points' z rows
    __shared__ float znv[4];
    __shared__ int   pn[4];
    __shared__ float gbv[32 * 4];
    __shared__ int   gbk[32 * 4];

    const int t = threadIdx.x;
    const int g = t >> 3, r = t & 7;
    const int C = *cnt;

    for (int base = blockIdx.x * 4; base < C; base += 2048 * 4) {
        const int npts = (C - base < 4) ? (C - base) : 4;

        __syncthreads();   // protect prior iteration's LDS reads
        if (t < 4) pn[t] = (t < npts) ? list[base + t] : -1;
        __syncthreads();
        for (int p = 0; p < npts; ++p) {
            const int n = pn[p];
            const int b = n >> 10, q = n & 1023;
            zsb[p * 264 + t] = z[(size_t)b * (ZC * 1024) + (size_t)t * 1024 + q];
        }
        __syncthreads();
        if (t < npts) znv[t] = np_sum256_sq(zsb + t * 264);

        float bv0 = 3.4e38f, bv1 = 3.4e38f, bv2 = 3.4e38f, bv3 = 3.4e38f;
        int   bk0 = 0x7fffffff, bk1 = 0x7fffffff, bk2 = 0x7fffffff, bk3 = 0x7fffffff;
        __syncthreads();   // znv visible

        for (int tile = 0; tile < 32; ++tile) {
            __syncthreads();
            const float4* src = reinterpret_cast<const float4*>(emb + (size_t)tile * 32 * ZC);
            #pragma unroll
            for (int i = 0; i < 8; ++i) {
                const int f = i * 256 + t;
                const int row = f >> 6, c4 = f & 63;
                *reinterpret_cast<float4*>(es + row * 264 + c4 * 4) = src[f];
            }
            __syncthreads();

            const float* er = es + g * 264;
            const float en = ens_np[tile * 32 + g];
            const int code = tile * 32 + g;

            #pragma unroll
            for (int p = 0; p < 4; ++p) {
                if (p < npts) {
                    const float* zp = zsb + p * 264;
                    double dd = 0.0;
                    #pragma unroll
                    for (int i = 0; i < 16; ++i) {
                        const int c = 8 * i + r;
                        dd = fma((double)er[c],       (double)zp[c],       dd);
                        dd = fma((double)er[128 + c], (double)zp[128 + c], dd);
                    }
                    #pragma unroll
                    for (int mk = 1; mk < 8; mk <<= 1) dd = dd + __shfl_xor(dd, mk);
                    if (r == 0) {
                        const float d = __fsub_rn(__fadd_rn(znv[p], en),
                                                  __fmul_rn(2.0f, (float)dd));
                        if (p == 0) { if (d < bv0) { bv0 = d; bk0 = code; } }
                        if (p == 1) { if (d < bv1) { bv1 = d; bk1 = code; } }
                        if (p == 2) { if (d < bv2) { bv2 = d; bk2 = code; } }
                        if (p == 3) { if (d < bv3) { bv3 = d; bk3 = code; } }
                    }
                }
            }
        }

        if (r == 0) {
            gbv[g * 4 + 0] = bv0; gbk[g * 4 + 0] = bk0;
            gbv[g * 4 + 1] = bv1; gbk[g * 4 + 1] = bk1;
            gbv[g * 4 + 2] = bv2; gbk[g * 4 + 2] = bk2;
            gbv[g * 4 + 3] = bv3; gbk[g * 4 + 3] = bk3;
        }
        __syncthreads();
        if (t < npts) {
            float bvv = gbv[0 * 4 + t]; int bkk = gbk[0 * 4 + t];
            for (int gg = 1; gg < 32; ++gg) {
                const float v = gbv[gg * 4 + t]; const int k = gbk[gg * 4 + t];
                if (v < bvv || (v == bvv && k < bkk)) { bvv = v; bkk = k; }
            }
            idxf[pn[t]] = (float)bkk;
        }
    }
}

// ---------------------------------------------------------------------------
// outputs (verified round 2) — overwrites the scratch regions.
// ---------------------------------------------------------------------------
__global__ __launch_bounds__(256)
void vq_outputs_kernel(const float* __restrict__ z, const float* __restrict__ emb,
                       const float* __restrict__ idxf,
                       float* __restrict__ out_q, float* __restrict__ out_loss)
{
    __shared__ float zts[32 * 257];
    __shared__ int   ids[32];

    const int t  = threadIdx.x;
    const int bh = blockIdx.x;
    const int b  = bh >> 5, h = bh & 31;
    const int n0 = bh * 32;

    if (t < 32) ids[t] = (int)idxf[n0 + t];
    __syncthreads();

    const size_t zbase = (size_t)b * (ZC * 1024) + h * 32;

    for (int rep = 0; rep < 32; ++rep) {
        const int flat = rep * 256 + t;
        const int c = flat >> 5;
        const int ww = flat & 31;
        const size_t ga = zbase + (size_t)c * 1024 + ww;
        const float zv = z[ga];
        zts[ww * 257 + c] = zv;
        out_q[ga] = emb[(size_t)ids[ww] * ZC + c];
    }
    __syncthreads();

    for (int rep = 0; rep < 32; ++rep) {
        const float e = emb[(size_t)ids[rep] * ZC + t];
        const float d = e - zts[rep * 257 + t];
        out_loss[(size_t)(n0 + rep) * ZC + t] = 1.25f * d * d;
    }
}

extern "C" void kernel_launch(void* const* d_in, const int* in_sizes, int n_in,
                              void* d_out, int out_size, void* d_ws, size_t ws_size,
                              hipStream_t stream)
{
    const float* z   = (const float*)d_in[0];   // [32,256,32,32]
    const float* emb = (const float*)d_in[1];   // [1024,256]
    float* out      = (float*)d_out;
    float* out_q    = out;                       // 8388608 floats
    float* out_loss = out + 8388608;             // 8388608 floats
    float* out_idx  = out + 16777216;            // 32768 floats

    // scratch carved from output regions (fully overwritten by final kernels):
    unsigned short* Ab = (unsigned short*)d_out;                       // 16 MiB (out_q)
    unsigned short* Bb = (unsigned short*)((char*)d_out + 33554432);   // 512 KiB
    float* ensg = (float*)((char*)d_out + 34603008);                   // 4 KiB
    int*   cnt  = (int*)  ((char*)d_out + 34607104);                   // 4 B
    int*   list = (int*)  ((char*)d_out + 34607168);                   // 128 KiB

    vq_prep_z        <<<4096, 256, 0, stream>>>(z, Ab);
    vq_prep_e        <<<128,  256, 0, stream>>>(emb, Bb);
    vq_ens_np        <<<32,   256, 0, stream>>>(emb, ensg, cnt);
    vq_gemm_argmin   <<<512,  256, 0, stream>>>(Ab, Bb, ensg, out_idx);
    vq_compact       <<<128,  256, 0, stream>>>(out_idx, cnt, list);
    vq_fixup3        <<<2048, 256, 0, stream>>>(z, emb, ensg, out_idx, cnt, list);
    vq_outputs_kernel<<<1024, 256, 0, stream>>>(z, emb, out_idx, out_q, out_loss);
}